// Round 1
// baseline (2184.278 us; speedup 1.0000x reference)
//
#include <hip/hip_runtime.h>
#include <stdint.h>

typedef __bf16 bf16x8 __attribute__((ext_vector_type(8)));
typedef float f32x4 __attribute__((ext_vector_type(4)));
typedef unsigned short ushort8 __attribute__((ext_vector_type(8)));

#define DEV static __device__ __forceinline__

DEV float bf2f(unsigned short h) {
  union { unsigned u; float f; } v; v.u = ((unsigned)h) << 16; return v.f;
}
DEV unsigned short f2bf(float f) {
  union { float f; unsigned u; } v; v.f = f;
  unsigned r = v.u + 0x7fffu + ((v.u >> 16) & 1u);  // RNE
  return (unsigned short)(r >> 16);
}
DEV float gelu_f(float x) {  // jax.nn.gelu approximate=True (tanh)
  const float c = 0.7978845608028654f;
  return 0.5f * x * (1.f + tanhf(c * (x + 0.044715f * x * x * x)));
}

struct Scalars { int active; int step_active; int steps; float t; float dt; };

// idx width probe (int64 -> (id,0,id,0,...) viewed as int32). Proven harmless.
__global__ void detect_idx_kernel(const int* idx, int* i64f) {
  __shared__ int anyOdd, anyEven;
  if (threadIdx.x == 0) { anyOdd = 0; anyEven = 0; }
  __syncthreads();
  for (int j = threadIdx.x; j < 1024; j += 256) {
    int v = idx[j];
    if (j & 1) { if (v != 0) anyOdd = 1; }
    else       { if (v != 0) anyEven = 1; }
  }
  __syncthreads();
  if (threadIdx.x == 0) *i64f = (anyOdd == 0 && anyEven == 1) ? 1 : 0;
}

__global__ void sentinel_kernel(float* out, float val) {
  if (val != 0.f) out[0] = val;
}

// ---------------------------------------------------------------------------
// MFMA bf16 GEMM: C[1024 x N] = A[1024 x K] * B[K x N]. 64x64 tiles,
// 4 waves x (2x2 16x16x32 frags). A: internal bf16. B: f32 external
// (stage-convert) or bf16 internal. Layouts per learn_hip m89/m120:
//   A-frag A[m=lane&15][k=quad*8+j]; B-frag B[k=quad*8+j][n=lane&15]
//   C/D: col=lane&15, row=quad*4+reg
// ---------------------------------------------------------------------------
enum { EPI_BF16 = 0, EPI_SCORES_BF16, EPI_GELU_BF16, EPI_F32, EPI_ADD_F32, EPI_COND_F32 };

struct GemmArgs {
  const unsigned short* A; int lda; long long aStrideZ;  // bf16
  const void* B; long long bOff; int ldb; long long bStrideZ;
  void* C; int ldc; long long cStrideZ;
  int K;
  const float* bias; long long biasOff;  // f32 (inputs proven f32)
  const float* addsrc;
  const int* exited;
  const int* guard;
};

template <bool BF32, bool TRANSB, int EPI>
__global__ __launch_bounds__(256) void gemm_mfma(GemmArgs g) {
  if (g.guard && *g.guard == 0) return;
  const int bm = blockIdx.x * 64;
  const int bn = blockIdx.y * 64;
  const int z = blockIdx.z;

  if constexpr (EPI == EPI_SCORES_BF16) {
    if (bn > bm + 63) {  // fully causal-masked tile: fill bf16(-1e9)
      unsigned short* C = (unsigned short*)g.C + (size_t)z * g.cStrideZ;
      unsigned short neg = f2bf(-1e9f);
      for (int t = threadIdx.x; t < 4096; t += 256) {
        int r = t >> 6, c = t & 63;
        C[(size_t)(bm + r) * g.ldc + bn + c] = neg;
      }
      return;
    }
  }

  __shared__ __align__(16) unsigned short As[64][40];  // [m][k], 80B row (16B-mult)
  __shared__ __align__(16) unsigned short Bs[64][40];  // [n][k]

  const int tid = threadIdx.x;
  const int lane = tid & 63;
  const int wave = tid >> 6;
  const int quad = lane >> 4, l16 = lane & 15;
  const int wr = (wave >> 1) * 32, wc = (wave & 1) * 32;
  const int rowA = tid >> 2, segA = (tid & 3) * 8;  // 64 rows x 32 k

  f32x4 acc[2][2] = {};
  const unsigned short* Az = g.A + (size_t)z * g.aStrideZ;

  for (int k0 = 0; k0 < g.K; k0 += 32) {
    // ---- stage A [64 x 32] bf16, direct vector copy
    *(ushort8*)&As[rowA][segA] =
        *(const ushort8*)(Az + (size_t)(bm + rowA) * g.lda + k0 + segA);
    // ---- stage B into Bs[n][k]
    if constexpr (TRANSB) {  // B given [N,K] bf16 (internal)
      const unsigned short* Bz =
          (const unsigned short*)g.B + g.bOff + (size_t)z * g.bStrideZ;
      *(ushort8*)&Bs[rowA][segA] =
          *(const ushort8*)(Bz + (size_t)(bn + rowA) * g.ldb + k0 + segA);
    } else {
      const int kk = tid >> 3, n0 = (tid & 7) * 8;  // 32 k-rows x 64 n
      if constexpr (BF32) {  // external f32 weights -> convert
        const float* Bz = (const float*)g.B + g.bOff + (size_t)z * g.bStrideZ;
        const float* p = Bz + (size_t)(k0 + kk) * g.ldb + bn + n0;
        float4 u = *(const float4*)p;
        float4 v2 = *(const float4*)(p + 4);
        Bs[n0 + 0][kk] = f2bf(u.x); Bs[n0 + 1][kk] = f2bf(u.y);
        Bs[n0 + 2][kk] = f2bf(u.z); Bs[n0 + 3][kk] = f2bf(u.w);
        Bs[n0 + 4][kk] = f2bf(v2.x); Bs[n0 + 5][kk] = f2bf(v2.y);
        Bs[n0 + 6][kk] = f2bf(v2.z); Bs[n0 + 7][kk] = f2bf(v2.w);
      } else {  // internal bf16 [K,N] (PV: V rows)
        const unsigned short* Bz =
            (const unsigned short*)g.B + g.bOff + (size_t)z * g.bStrideZ;
        ushort8 v = *(const ushort8*)(Bz + (size_t)(k0 + kk) * g.ldb + bn + n0);
#pragma unroll
        for (int j = 0; j < 8; ++j) Bs[n0 + j][kk] = v[j];
      }
    }
    __syncthreads();

    bf16x8 a0 = *(const bf16x8*)&As[wr + l16][quad * 8];
    bf16x8 a1 = *(const bf16x8*)&As[wr + 16 + l16][quad * 8];
    bf16x8 b0 = *(const bf16x8*)&Bs[wc + l16][quad * 8];
    bf16x8 b1 = *(const bf16x8*)&Bs[wc + 16 + l16][quad * 8];
    acc[0][0] = __builtin_amdgcn_mfma_f32_16x16x32_bf16(a0, b0, acc[0][0], 0, 0, 0);
    acc[0][1] = __builtin_amdgcn_mfma_f32_16x16x32_bf16(a0, b1, acc[0][1], 0, 0, 0);
    acc[1][0] = __builtin_amdgcn_mfma_f32_16x16x32_bf16(a1, b0, acc[1][0], 0, 0, 0);
    acc[1][1] = __builtin_amdgcn_mfma_f32_16x16x32_bf16(a1, b1, acc[1][1], 0, 0, 0);
    __syncthreads();
  }

#pragma unroll
  for (int i = 0; i < 2; ++i) {
#pragma unroll
    for (int j = 0; j < 2; ++j) {
#pragma unroll
      for (int r = 0; r < 4; ++r) {
        int row = bm + wr + i * 16 + quad * 4 + r;
        int col = bn + wc + j * 16 + l16;
        float val = acc[i][j][r];
        if constexpr (EPI == EPI_BF16) {
          ((unsigned short*)g.C)[(size_t)z * g.cStrideZ + (size_t)row * g.ldc + col] =
              f2bf(val);
        } else if constexpr (EPI == EPI_SCORES_BF16) {
          float o = (col <= row) ? val * 0.125f : -1e9f;  // 1/sqrt(64) + causal
          ((unsigned short*)g.C)[(size_t)z * g.cStrideZ + (size_t)row * g.ldc + col] =
              f2bf(o);
        } else if constexpr (EPI == EPI_GELU_BF16) {
          ((unsigned short*)g.C)[(size_t)row * g.ldc + col] =
              f2bf(gelu_f(val + g.bias[g.biasOff + col]));
        } else if constexpr (EPI == EPI_F32) {
          ((float*)g.C)[(size_t)z * g.cStrideZ + (size_t)row * g.ldc + col] = val;
        } else if constexpr (EPI == EPI_ADD_F32) {
          ((float*)g.C)[(size_t)row * g.ldc + col] =
              val + g.bias[g.biasOff + col] + g.addsrc[(size_t)row * g.ldc + col];
        } else if constexpr (EPI == EPI_COND_F32) {
          if (!g.exited[row])
            ((float*)g.C)[(size_t)row * g.ldc + col] = val;
        }
      }
    }
  }
}

// ---------------------------------------------------------------------------
// Small kernels (f32 state, bf16 MFMA feeds)
// ---------------------------------------------------------------------------
__global__ void embed_kernel(const float* wte, const float* wpe, const int* idx,
                             float* z_prev, int* exited, const int* i64f) {
  int tok = blockIdx.x, d = threadIdx.x;
  int id = (*i64f) ? idx[2 * tok] : idx[tok];
  z_prev[tok * 256 + d] = wte[(size_t)id * 256 + d] + wpe[(size_t)tok * 256 + d];
  if (d == 0) exited[tok] = 0;
}

__global__ void initblk_kernel(float* z_s, const float* z_prev, Scalars* sc) {
  int i = blockIdx.x * 256 + threadIdx.x;
  ((float4*)z_s)[i] = ((const float4*)z_prev)[i];
  if (i == 0) { sc->active = 1; sc->step_active = 0; sc->t = 0.f; sc->steps = 0; sc->dt = 0.f; }
}

// layernorm: f32 in -> bf16 out (MFMA A-operand), one wave per token
__global__ void ln_kernel(const float* x, const float* gg, const float* bb, int goff,
                          unsigned short* out, const int* guard) {
  if (guard && *guard == 0) return;
  int wave = threadIdx.x >> 6, lane = threadIdx.x & 63;
  int tok = blockIdx.x * 4 + wave;
  const float* p = x + (size_t)tok * 256;
  float v[4];
  float s = 0.f, s2 = 0.f;
#pragma unroll
  for (int j = 0; j < 4; ++j) { v[j] = p[lane + 64 * j]; s += v[j]; s2 += v[j] * v[j]; }
#pragma unroll
  for (int o = 1; o < 64; o <<= 1) { s += __shfl_xor(s, o); s2 += __shfl_xor(s2, o); }
  float mean = s * (1.f / 256.f);
  float var = s2 * (1.f / 256.f) - mean * mean;
  float rstd = rsqrtf(var + 1e-5f);
#pragma unroll
  for (int j = 0; j < 4; ++j) {
    int d = lane + 64 * j;
    out[(size_t)tok * 256 + d] = f2bf((v[j] - mean) * rstd * gg[goff + d] + bb[goff + d]);
  }
}

// softmax in-place over bf16 rows of S[head][1024][1024]
__global__ __launch_bounds__(256) void softmax_kernel(unsigned short* S,
                                                      const int* guard) {
  if (*guard == 0) return;
  int row = blockIdx.x, h = blockIdx.y;
  unsigned short* p = S + ((size_t)h << 20) + ((size_t)row << 10);
  int t = threadIdx.x, lane = t & 63, wave = t >> 6;
  ushort4 u = ((ushort4*)p)[t];
  float v0 = bf2f(u.x), v1 = bf2f(u.y), v2 = bf2f(u.z), v3 = bf2f(u.w);
  float m = fmaxf(fmaxf(v0, v1), fmaxf(v2, v3));
#pragma unroll
  for (int o = 32; o; o >>= 1) m = fmaxf(m, __shfl_xor(m, o));
  __shared__ float red[4];
  if (lane == 0) red[wave] = m;
  __syncthreads();
  m = fmaxf(fmaxf(red[0], red[1]), fmaxf(red[2], red[3]));
  float e0 = expf(v0 - m), e1 = expf(v1 - m), e2 = expf(v2 - m), e3 = expf(v3 - m);
  float s = e0 + e1 + e2 + e3;
#pragma unroll
  for (int o = 32; o; o >>= 1) s += __shfl_xor(s, o);
  __syncthreads();
  if (lane == 0) red[wave] = s;
  __syncthreads();
  s = red[0] + red[1] + red[2] + red[3];
  float inv = 1.f / s;
  ushort4 w; w.x = f2bf(e0 * inv); w.y = f2bf(e1 * inv);
  w.z = f2bf(e2 * inv); w.w = f2bf(e3 * inv);
  ((ushort4*)p)[t] = w;
}

__global__ void norm_kernel(const float* dz, float* norms, const int* guard) {
  if (*guard == 0) return;
  int wave = threadIdx.x >> 6, lane = threadIdx.x & 63;
  int tok = blockIdx.x * 4 + wave;
  const float* p = dz + (size_t)tok * 256;
  float s = 0.f;
#pragma unroll
  for (int j = 0; j < 4; ++j) { float v = p[lane + 64 * j]; s += v * v; }
#pragma unroll
  for (int o = 32; o; o >>= 1) s += __shfl_down(s, o);
  if (lane == 0) norms[tok] = sqrtf(s);
}

__global__ __launch_bounds__(1024) void scalar_kernel(const float* norms, Scalars* sc) {
  __shared__ float red[1024];
  if (sc->active == 0) { if (threadIdx.x == 0) sc->step_active = 0; return; }
  int t = threadIdx.x;
  red[t] = norms[t];
  __syncthreads();
  for (int o = 512; o; o >>= 1) { if (t < o) red[t] += red[t + o]; __syncthreads(); }
  if (t == 0) {
    float mc = red[0] * (1.f / 1024.f);
    float scale = fminf(fmaxf(1.f / (1.f + mc), 0.5f), 2.f);
    float dt = fminf(0.5f * scale, 1.f - sc->t);  // dt_base = 1/MIN_STEPS
    sc->dt = dt;
    sc->step_active = 1;
    float tn = sc->t + dt;
    int steps = sc->steps + 1;
    sc->t = tn;
    sc->steps = steps;
    int conv = (dt * mc < 0.1f) && (steps >= 2);  // ||z_new-z|| = dt*||dz||
    sc->active = ((tn < 1.f - 1e-6f) && !conv) ? 1 : 0;
  }
}

__global__ void update_kernel(float* z_s, const float* dz, const Scalars* sc) {
  if (sc->step_active == 0) return;
  float dt = sc->dt;
  int i = blockIdx.x * 256 + threadIdx.x;
  float4 z = ((float4*)z_s)[i];
  float4 d = ((const float4*)dz)[i];
  z.x += dt * d.x; z.y += dt * d.y; z.z += dt * d.z; z.w += dt * d.w;
  ((float4*)z_s)[i] = z;
}

__global__ void combine_kernel(float* z_prev, const float* z_s, const int* exited) {
  int i = blockIdx.x * 256 + threadIdx.x;
  int tok = i >> 6;
  if (exited[tok]) return;
  float4 a = ((float4*)z_prev)[i];
  float4 b = ((const float4*)z_s)[i];
  a.x += b.x; a.y += b.y; a.z += b.z; a.w += b.w;
  ((float4*)z_prev)[i] = a;
}

__global__ __launch_bounds__(256) void conf_kernel(const float* logits, int* exited) {
  int tok = blockIdx.x;
  if (exited[tok]) return;
  const float* p = logits + ((size_t)tok << 14);
  int t = threadIdx.x, lane = t & 63, wave = t >> 6;
  float m = -1e30f;
  for (int j = t; j < 16384; j += 256) m = fmaxf(m, p[j]);
#pragma unroll
  for (int o = 32; o; o >>= 1) m = fmaxf(m, __shfl_xor(m, o));
  __shared__ float red[4];
  if (lane == 0) red[wave] = m;
  __syncthreads();
  m = fmaxf(fmaxf(red[0], red[1]), fmaxf(red[2], red[3]));
  float s = 0.f;
  for (int j = t; j < 16384; j += 256) s += expf(p[j] - m);
#pragma unroll
  for (int o = 32; o; o >>= 1) s += __shfl_xor(s, o);
  __syncthreads();
  if (lane == 0) red[wave] = s;
  __syncthreads();
  s = red[0] + red[1] + red[2] + red[3];
  if (t == 0 && (1.f / s) > 0.9f) exited[tok] = 1;
}

// ---------------------------------------------------------------------------
// Host launch
// ---------------------------------------------------------------------------
extern "C" void kernel_launch(void* const* d_in, const int* in_sizes, int n_in,
                              void* d_out, int out_size, void* d_ws, size_t ws_size,
                              hipStream_t stream) {
  (void)out_size;
  const float* wte   = (const float*)d_in[0];
  const float* wpe   = (const float*)d_in[1];
  const float* ln1_g = (const float*)d_in[2];
  const float* ln1_b = (const float*)d_in[3];
  const float* wqkv  = (const float*)d_in[4];
  const float* wo    = (const float*)d_in[5];
  const float* ln2_g = (const float*)d_in[6];
  const float* ln2_b = (const float*)d_in[7];
  const float* w1    = (const float*)d_in[8];
  const float* b1    = (const float*)d_in[9];
  const float* w2    = (const float*)d_in[10];
  const float* b2    = (const float*)d_in[11];
  const float* eln_g = (const float*)d_in[12];
  const float* eln_b = (const float*)d_in[13];
  const float* ehead = (const float*)d_in[14];
  const int* idx = (const int*)d_in[15];
  float* out = (float*)d_out;  // f32 output (proven round 5)

  float sentinel = 0.f;
  if (!(n_in == 16 && in_sizes[0] == 4194304 && in_sizes[14] == 16777216 &&
        in_sizes[15] == 1024))
    sentinel += 1000.f;
  if (ws_size < (size_t)20000000) sentinel += 2000.f;

  char* w = (char*)d_ws;
  auto alloc = [&](size_t bytes) {
    char* p = w; w += (bytes + 255) & ~(size_t)255; return p;
  };
  int* i64f        = (int*)alloc(256);
  Scalars* sc      = (Scalars*)alloc(sizeof(Scalars));
  int* exited      = (int*)alloc(1024 * 4);
  float* norms     = (float*)alloc(1024 * 4);
  float* z_prev    = (float*)alloc(1024 * 256 * 4);
  float* z_s       = (float*)alloc(1024 * 256 * 4);
  float* attnout   = (float*)alloc(1024 * 256 * 4);
  float* dz        = (float*)alloc(1024 * 256 * 4);
  unsigned short* xln  = (unsigned short*)alloc(1024 * 256 * 2);
  unsigned short* hln  = (unsigned short*)alloc(1024 * 256 * 2);
  unsigned short* zn   = (unsigned short*)alloc(1024 * 256 * 2);
  unsigned short* qkvb = (unsigned short*)alloc((size_t)1024 * 768 * 2);
  unsigned short* obuf = (unsigned short*)alloc(1024 * 256 * 2);
  unsigned short* hmid = (unsigned short*)alloc((size_t)1024 * 1024 * 2);
  unsigned short* Sbuf = (unsigned short*)alloc((size_t)4 * 1024 * 1024 * 2);  // 8 MB
  const int* guard = &sc->active;

  detect_idx_kernel<<<1, 256, 0, stream>>>(idx, i64f);
  embed_kernel<<<1024, 256, 0, stream>>>(wte, wpe, idx, z_prev, exited, i64f);

  for (int i = 0; i < 4; ++i) {
    initblk_kernel<<<256, 256, 0, stream>>>(z_s, z_prev, sc);
    for (int s = 0; s < 4; ++s) {
      ln_kernel<<<256, 256, 0, stream>>>(z_s, ln1_g, ln1_b, i * 256, xln, guard);
      {  // qkv = ln1(z) @ wqkv[i] -> bf16 [1024,768]
        GemmArgs a{}; a.A = xln; a.lda = 256;
        a.B = wqkv; a.bOff = (long long)i * 196608; a.ldb = 768;
        a.C = qkvb; a.ldc = 768; a.K = 256; a.guard = guard;
        gemm_mfma<true, false, EPI_BF16><<<dim3(16, 12, 1), 256, 0, stream>>>(a);
      }
      {  // S_h = Q_h @ K_h^T * 0.125 causal -> bf16, batched over heads
        GemmArgs a{}; a.A = qkvb; a.lda = 768; a.aStrideZ = 64;
        a.B = qkvb; a.bOff = 256; a.ldb = 768; a.bStrideZ = 64;
        a.C = Sbuf; a.ldc = 1024; a.cStrideZ = 1048576; a.K = 64; a.guard = guard;
        gemm_mfma<false, true, EPI_SCORES_BF16><<<dim3(16, 16, 4), 256, 0, stream>>>(a);
      }
      softmax_kernel<<<dim3(1024, 4), 256, 0, stream>>>(Sbuf, guard);
      {  // O_h = P_h @ V_h -> obuf bf16 [1024,256]
        GemmArgs a{}; a.A = Sbuf; a.lda = 1024; a.aStrideZ = 1048576;
        a.B = qkvb; a.bOff = 512; a.ldb = 768; a.bStrideZ = 64;
        a.C = obuf; a.ldc = 256; a.cStrideZ = 64; a.K = 1024; a.guard = guard;
        gemm_mfma<false, false, EPI_BF16><<<dim3(16, 1, 4), 256, 0, stream>>>(a);
      }
      {  // attnout = O @ wo[i] -> f32
        GemmArgs a{}; a.A = obuf; a.lda = 256;
        a.B = wo; a.bOff = (long long)i * 65536; a.ldb = 256;
        a.C = attnout; a.ldc = 256; a.K = 256; a.guard = guard;
        gemm_mfma<true, false, EPI_F32><<<dim3(16, 4, 1), 256, 0, stream>>>(a);
      }
      ln_kernel<<<256, 256, 0, stream>>>(z_s, ln2_g, ln2_b, i * 256, hln, guard);
      {  // hmid = gelu(ln2(z) @ w1[i] + b1[i]) -> bf16
        GemmArgs a{}; a.A = hln; a.lda = 256;
        a.B = w1; a.bOff = (long long)i * 262144; a.ldb = 1024;
        a.C = hmid; a.ldc = 1024; a.K = 256;
        a.bias = b1; a.biasOff = i * 1024; a.guard = guard;
        gemm_mfma<true, false, EPI_GELU_BF16><<<dim3(16, 16, 1), 256, 0, stream>>>(a);
      }
      {  // dz = hmid @ w2[i] + b2[i] + attnout -> f32
        GemmArgs a{}; a.A = hmid; a.lda = 1024;
        a.B = w2; a.bOff = (long long)i * 262144; a.ldb = 256;
        a.C = dz; a.ldc = 256; a.K = 1024;
        a.bias = b2; a.biasOff = i * 256; a.addsrc = attnout; a.guard = guard;
        gemm_mfma<true, false, EPI_ADD_F32><<<dim3(16, 4, 1), 256, 0, stream>>>(a);
      }
      norm_kernel<<<256, 256, 0, stream>>>(dz, norms, guard);
      scalar_kernel<<<1, 1024, 0, stream>>>(norms, sc);
      update_kernel<<<256, 256, 0, stream>>>(z_s, dz, sc);
    }
    combine_kernel<<<256, 256, 0, stream>>>(z_prev, z_s, exited);
    ln_kernel<<<256, 256, 0, stream>>>(z_prev, eln_g, eln_b, i * 256, zn, nullptr);
    {  // blk_logits = ln(z) @ ehead[i] -> d_out (f32) where !exited
      GemmArgs a{}; a.A = zn; a.lda = 256;
      a.B = ehead; a.bOff = (long long)i * 4194304; a.ldb = 16384;
      a.C = out; a.ldc = 16384; a.K = 256; a.exited = exited;
      gemm_mfma<true, false, EPI_COND_F32><<<dim3(16, 256, 1), 256, 0, stream>>>(a);
    }
    if (i >= 1) conf_kernel<<<1024, 256, 0, stream>>>(out, exited);
  }

  sentinel_kernel<<<1, 1, 0, stream>>>(out, sentinel);
}

// Round 2
// 1641.604 us; speedup vs baseline: 1.3306x; 1.3306x over previous
//
#include <hip/hip_runtime.h>
#include <stdint.h>

typedef __bf16 bf16x8 __attribute__((ext_vector_type(8)));
typedef float f32x4 __attribute__((ext_vector_type(4)));
typedef unsigned short ushort8 __attribute__((ext_vector_type(8)));

#define DEV static __device__ __forceinline__

DEV float bf2f(unsigned short h) {
  union { unsigned u; float f; } v; v.u = ((unsigned)h) << 16; return v.f;
}
DEV unsigned short f2bf(float f) {
  union { float f; unsigned u; } v; v.f = f;
  unsigned r = v.u + 0x7fffu + ((v.u >> 16) & 1u);  // RNE
  return (unsigned short)(r >> 16);
}
DEV float gelu_f(float x) {  // jax.nn.gelu approximate=True (tanh)
  const float c = 0.7978845608028654f;
  return 0.5f * x * (1.f + tanhf(c * (x + 0.044715f * x * x * x)));
}

struct Scalars { int active; int step_active; int steps; float t; float dt; };

// idx width probe (int64 -> (id,0,id,0,...) viewed as int32). Proven harmless.
__global__ void detect_idx_kernel(const int* idx, int* i64f) {
  __shared__ int anyOdd, anyEven;
  if (threadIdx.x == 0) { anyOdd = 0; anyEven = 0; }
  __syncthreads();
  for (int j = threadIdx.x; j < 1024; j += 256) {
    int v = idx[j];
    if (j & 1) { if (v != 0) anyOdd = 1; }
    else       { if (v != 0) anyEven = 1; }
  }
  __syncthreads();
  if (threadIdx.x == 0) *i64f = (anyOdd == 0 && anyEven == 1) ? 1 : 0;
}

__global__ void sentinel_kernel(float* out, float val) {
  if (val != 0.f) out[0] = val;
}

// ---------------------------------------------------------------------------
// Transpose-convert: src f32 [R][C] row-major -> dst bf16 [C][R] row-major.
// One 64x64 tile per block via padded LDS. Conflict-free-ish, one-time cost.
// ---------------------------------------------------------------------------
DEV void tr_tile(const float* src, unsigned short* dst, int R, int C,
                 int tx, int ty, float (*lds)[65]) {
  const int tid = threadIdx.x;
#pragma unroll
  for (int jj = 0; jj < 4; ++jj) {
    int r = jj * 16 + (tid >> 4);
    int c = (tid & 15) * 4;
    float4 v = *(const float4*)&src[(size_t)(ty * 64 + r) * C + tx * 64 + c];
    lds[r][c] = v.x; lds[r][c + 1] = v.y; lds[r][c + 2] = v.z; lds[r][c + 3] = v.w;
  }
  __syncthreads();
  const int lr = tid >> 2, seg = (tid & 3) * 16;
  ushort8 o0, o1;
#pragma unroll
  for (int e = 0; e < 8; ++e) o0[e] = f2bf(lds[seg + e][lr]);
#pragma unroll
  for (int e = 0; e < 8; ++e) o1[e] = f2bf(lds[seg + 8 + e][lr]);
  unsigned short* dp = dst + (size_t)(tx * 64 + lr) * R + ty * 64 + seg;
  *(ushort8*)dp = o0;
  *(ushort8*)(dp + 8) = o1;
}

// All four weight matrices of one layer in one launch (192 tiles).
__global__ __launch_bounds__(256) void tr_weights_kernel(
    const float* wqkv, const float* wo, const float* w1, const float* w2,
    unsigned short* qkvT, unsigned short* woT, unsigned short* w1T,
    unsigned short* w2T) {
  __shared__ float lds[64][65];
  int t = blockIdx.x;
  if (t < 48)       { tr_tile(wqkv, qkvT, 256, 768, t % 12, t / 12, lds); }
  else if (t < 64)  { t -= 48;  tr_tile(wo, woT, 256, 256, t % 4, t / 4, lds); }
  else if (t < 128) { t -= 64;  tr_tile(w1, w1T, 256, 1024, t % 16, t / 16, lds); }
  else              { t -= 128; tr_tile(w2, w2T, 1024, 256, t % 4, t / 4, lds); }
}

// ehead[i] f32 [256][16384] -> bheadT bf16 [16384][256] (into Sbuf).
__global__ __launch_bounds__(256) void tr_mat_kernel(const float* src,
                                                     unsigned short* dst) {
  __shared__ float lds[64][65];
  tr_tile(src, dst, 256, 16384, blockIdx.x, blockIdx.y, lds);
}

// ---------------------------------------------------------------------------
// MFMA bf16 GEMM: C[1024 x N] = A[1024 x K] * B^T. 64x64 tiles, 4 waves x
// (2x2 16x16x32 frags). A bf16 [M,K]; B bf16 [N,K] (all pre-transposed).
// Vector ushort8 staging both sides -> ~2-way LDS banking (free per m136).
//   A-frag A[m=lane&15][k=quad*8+j]; B-frag B[k=quad*8+j][n=lane&15]
//   C/D: col=lane&15, row=quad*4+reg
// ---------------------------------------------------------------------------
enum { EPI_BF16 = 0, EPI_SCORES_BF16, EPI_GELU_BF16, EPI_F32, EPI_ADD_F32,
       EPI_COND_F32, EPI_QKV_BF16 };

struct GemmArgs {
  const unsigned short* A; int lda; long long aStrideZ;  // bf16 [M,K]
  const unsigned short* B; long long bOff; int ldb; long long bStrideZ;  // bf16 [N,K]
  void* C; int ldc; long long cStrideZ;
  int K;
  const float* bias; long long biasOff;  // f32
  const float* addsrc;
  const int* exited;
  const int* guard;
  unsigned short* C2;  // EPI_QKV: VT[4][64][1024] transposed V copy
  int causalK;         // PV: kLimit = bm + 64
  int xcdswz;          // XCD-contiguous block remap (grid blocks % 8 == 0)
};

template <int EPI>
__global__ __launch_bounds__(256) void gemm_mfma(GemmArgs g) {
  if (g.guard && *g.guard == 0) return;
  int bx = blockIdx.x, by = blockIdx.y;
  if (g.xcdswz) {
    int lin = bx + gridDim.x * by;
    int cpx = (gridDim.x * gridDim.y) >> 3;
    int s2 = (lin & 7) * cpx + (lin >> 3);  // bijective: 4096 % 8 == 0
    bx = s2 % gridDim.x; by = s2 / gridDim.x;
  }
  const int bm = bx * 64;
  const int bn = by * 64;
  const int z = blockIdx.z;

  if constexpr (EPI == EPI_SCORES_BF16) {
    if (bn > bm) return;  // fully-masked tile: never read (softmax/PV clamp)
  }

  __shared__ __align__(16) unsigned short As[64][40];  // [m][k], 80B row
  __shared__ __align__(16) unsigned short Bs[64][40];  // [n][k]

  const int tid = threadIdx.x;
  const int lane = tid & 63;
  const int wave = tid >> 6;
  const int quad = lane >> 4, l16 = lane & 15;
  const int wr = (wave >> 1) * 32, wc = (wave & 1) * 32;
  const int rowA = tid >> 2, segA = (tid & 3) * 8;  // 64 rows x 32 k

  f32x4 acc[2][2] = {};
  const unsigned short* Az = g.A + (size_t)z * g.aStrideZ;
  const unsigned short* Bz = g.B + g.bOff + (size_t)z * g.bStrideZ;
  const int kLimit = g.causalK ? (bm + 64) : g.K;

  for (int k0 = 0; k0 < kLimit; k0 += 32) {
    *(ushort8*)&As[rowA][segA] =
        *(const ushort8*)(Az + (size_t)(bm + rowA) * g.lda + k0 + segA);
    *(ushort8*)&Bs[rowA][segA] =
        *(const ushort8*)(Bz + (size_t)(bn + rowA) * g.ldb + k0 + segA);
    __syncthreads();

    bf16x8 a0 = *(const bf16x8*)&As[wr + l16][quad * 8];
    bf16x8 a1 = *(const bf16x8*)&As[wr + 16 + l16][quad * 8];
    bf16x8 b0 = *(const bf16x8*)&Bs[wc + l16][quad * 8];
    bf16x8 b1 = *(const bf16x8*)&Bs[wc + 16 + l16][quad * 8];
    acc[0][0] = __builtin_amdgcn_mfma_f32_16x16x32_bf16(a0, b0, acc[0][0], 0, 0, 0);
    acc[0][1] = __builtin_amdgcn_mfma_f32_16x16x32_bf16(a0, b1, acc[0][1], 0, 0, 0);
    acc[1][0] = __builtin_amdgcn_mfma_f32_16x16x32_bf16(a1, b0, acc[1][0], 0, 0, 0);
    acc[1][1] = __builtin_amdgcn_mfma_f32_16x16x32_bf16(a1, b1, acc[1][1], 0, 0, 0);
    __syncthreads();
  }

#pragma unroll
  for (int i = 0; i < 2; ++i) {
#pragma unroll
    for (int j = 0; j < 2; ++j) {
#pragma unroll
      for (int r = 0; r < 4; ++r) {
        int row = bm + wr + i * 16 + quad * 4 + r;
        int col = bn + wc + j * 16 + l16;
        float val = acc[i][j][r];
        if constexpr (EPI == EPI_BF16) {
          ((unsigned short*)g.C)[(size_t)z * g.cStrideZ + (size_t)row * g.ldc + col] =
              f2bf(val);
        } else if constexpr (EPI == EPI_QKV_BF16) {
          unsigned short bv = f2bf(val);
          ((unsigned short*)g.C)[(size_t)row * g.ldc + col] = bv;
          if (col >= 512) {  // also write V transposed: VT[h][hd][tok]
            int cc = col - 512;
            g.C2[((cc >> 6) << 16) + ((cc & 63) << 10) + row] = bv;
          }
        } else if constexpr (EPI == EPI_SCORES_BF16) {
          float o = (col <= row) ? val * 0.125f : -1e9f;  // 1/sqrt(64) + causal
          ((unsigned short*)g.C)[(size_t)z * g.cStrideZ + (size_t)row * g.ldc + col] =
              f2bf(o);
        } else if constexpr (EPI == EPI_GELU_BF16) {
          ((unsigned short*)g.C)[(size_t)row * g.ldc + col] =
              f2bf(gelu_f(val + g.bias[g.biasOff + col]));
        } else if constexpr (EPI == EPI_F32) {
          ((float*)g.C)[(size_t)z * g.cStrideZ + (size_t)row * g.ldc + col] = val;
        } else if constexpr (EPI == EPI_ADD_F32) {
          ((float*)g.C)[(size_t)row * g.ldc + col] =
              val + g.bias[g.biasOff + col] + g.addsrc[(size_t)row * g.ldc + col];
        } else if constexpr (EPI == EPI_COND_F32) {
          if (!g.exited[row])
            ((float*)g.C)[(size_t)row * g.ldc + col] = val;
        }
      }
    }
  }
}

// ---------------------------------------------------------------------------
// Small kernels (f32 state, bf16 MFMA feeds)
// ---------------------------------------------------------------------------
__global__ void embed_kernel(const float* wte, const float* wpe, const int* idx,
                             float* z_prev, int* exited, const int* i64f) {
  int tok = blockIdx.x, d = threadIdx.x;
  int id = (*i64f) ? idx[2 * tok] : idx[tok];
  z_prev[tok * 256 + d] = wte[(size_t)id * 256 + d] + wpe[(size_t)tok * 256 + d];
  if (d == 0) exited[tok] = 0;
}

__global__ void initblk_kernel(float* z_s, const float* z_prev, Scalars* sc) {
  int i = blockIdx.x * 256 + threadIdx.x;
  ((float4*)z_s)[i] = ((const float4*)z_prev)[i];
  if (i == 0) { sc->active = 1; sc->step_active = 0; sc->t = 0.f; sc->steps = 0; sc->dt = 0.f; }
}

// layernorm: f32 in -> bf16 out (MFMA A-operand), one wave per token
__global__ void ln_kernel(const float* x, const float* gg, const float* bb, int goff,
                          unsigned short* out, const int* guard) {
  if (guard && *guard == 0) return;
  int wave = threadIdx.x >> 6, lane = threadIdx.x & 63;
  int tok = blockIdx.x * 4 + wave;
  const float* p = x + (size_t)tok * 256;
  float v[4];
  float s = 0.f, s2 = 0.f;
#pragma unroll
  for (int j = 0; j < 4; ++j) { v[j] = p[lane + 64 * j]; s += v[j]; s2 += v[j] * v[j]; }
#pragma unroll
  for (int o = 1; o < 64; o <<= 1) { s += __shfl_xor(s, o); s2 += __shfl_xor(s2, o); }
  float mean = s * (1.f / 256.f);
  float var = s2 * (1.f / 256.f) - mean * mean;
  float rstd = rsqrtf(var + 1e-5f);
#pragma unroll
  for (int j = 0; j < 4; ++j) {
    int d = lane + 64 * j;
    out[(size_t)tok * 256 + d] = f2bf((v[j] - mean) * rstd * gg[goff + d] + bb[goff + d]);
  }
}

// softmax in-place over bf16 rows of S[head][1024][1024], clamped to the
// causal prefix (cols < rowEnd = diagonal-tile end). Cols beyond rowEnd are
// never read downstream (PV clamps K to bm+64 == rowEnd).
__global__ __launch_bounds__(256) void softmax_kernel(unsigned short* S,
                                                      const int* guard) {
  if (*guard == 0) return;
  int row = blockIdx.x, h = blockIdx.y;
  unsigned short* p = S + ((size_t)h << 20) + ((size_t)row << 10);
  int t = threadIdx.x, lane = t & 63, wave = t >> 6;
  int rowEnd = (row & ~63) + 64;
  bool act = (t * 4) < rowEnd;
  float v0 = -1e30f, v1 = -1e30f, v2 = -1e30f, v3 = -1e30f;
  if (act) {
    ushort4 u = ((ushort4*)p)[t];
    v0 = bf2f(u.x); v1 = bf2f(u.y); v2 = bf2f(u.z); v3 = bf2f(u.w);
  }
  float m = fmaxf(fmaxf(v0, v1), fmaxf(v2, v3));
#pragma unroll
  for (int o = 32; o; o >>= 1) m = fmaxf(m, __shfl_xor(m, o));
  __shared__ float red[4];
  if (lane == 0) red[wave] = m;
  __syncthreads();
  m = fmaxf(fmaxf(red[0], red[1]), fmaxf(red[2], red[3]));
  float e0 = expf(v0 - m), e1 = expf(v1 - m), e2 = expf(v2 - m), e3 = expf(v3 - m);
  float s = e0 + e1 + e2 + e3;
#pragma unroll
  for (int o = 32; o; o >>= 1) s += __shfl_xor(s, o);
  __syncthreads();
  if (lane == 0) red[wave] = s;
  __syncthreads();
  s = red[0] + red[1] + red[2] + red[3];
  float inv = 1.f / s;
  if (act) {
    ushort4 w; w.x = f2bf(e0 * inv); w.y = f2bf(e1 * inv);
    w.z = f2bf(e2 * inv); w.w = f2bf(e3 * inv);
    ((ushort4*)p)[t] = w;
  }
}

__global__ void norm_kernel(const float* dz, float* norms, const int* guard) {
  if (*guard == 0) return;
  int wave = threadIdx.x >> 6, lane = threadIdx.x & 63;
  int tok = blockIdx.x * 4 + wave;
  const float* p = dz + (size_t)tok * 256;
  float s = 0.f;
#pragma unroll
  for (int j = 0; j < 4; ++j) { float v = p[lane + 64 * j]; s += v * v; }
#pragma unroll
  for (int o = 32; o; o >>= 1) s += __shfl_down(s, o);
  if (lane == 0) norms[tok] = sqrtf(s);
}

__global__ __launch_bounds__(1024) void scalar_kernel(const float* norms, Scalars* sc) {
  __shared__ float red[1024];
  if (sc->active == 0) { if (threadIdx.x == 0) sc->step_active = 0; return; }
  int t = threadIdx.x;
  red[t] = norms[t];
  __syncthreads();
  for (int o = 512; o; o >>= 1) { if (t < o) red[t] += red[t + o]; __syncthreads(); }
  if (t == 0) {
    float mc = red[0] * (1.f / 1024.f);
    float scale = fminf(fmaxf(1.f / (1.f + mc), 0.5f), 2.f);
    float dt = fminf(0.5f * scale, 1.f - sc->t);  // dt_base = 1/MIN_STEPS
    sc->dt = dt;
    sc->step_active = 1;
    float tn = sc->t + dt;
    int steps = sc->steps + 1;
    sc->t = tn;
    sc->steps = steps;
    int conv = (dt * mc < 0.1f) && (steps >= 2);  // ||z_new-z|| = dt*||dz||
    sc->active = ((tn < 1.f - 1e-6f) && !conv) ? 1 : 0;
  }
}

__global__ void update_kernel(float* z_s, const float* dz, const Scalars* sc) {
  if (sc->step_active == 0) return;
  float dt = sc->dt;
  int i = blockIdx.x * 256 + threadIdx.x;
  float4 z = ((float4*)z_s)[i];
  float4 d = ((const float4*)dz)[i];
  z.x += dt * d.x; z.y += dt * d.y; z.z += dt * d.z; z.w += dt * d.w;
  ((float4*)z_s)[i] = z;
}

__global__ void combine_kernel(float* z_prev, const float* z_s, const int* exited) {
  int i = blockIdx.x * 256 + threadIdx.x;
  int tok = i >> 6;
  if (exited[tok]) return;
  float4 a = ((float4*)z_prev)[i];
  float4 b = ((const float4*)z_s)[i];
  a.x += b.x; a.y += b.y; a.z += b.z; a.w += b.w;
  ((float4*)z_prev)[i] = a;
}

__global__ __launch_bounds__(256) void conf_kernel(const float* logits, int* exited) {
  int tok = blockIdx.x;
  if (exited[tok]) return;
  const float* p = logits + ((size_t)tok << 14);
  int t = threadIdx.x, lane = t & 63, wave = t >> 6;
  float m = -1e30f;
  for (int j = t; j < 16384; j += 256) m = fmaxf(m, p[j]);
#pragma unroll
  for (int o = 32; o; o >>= 1) m = fmaxf(m, __shfl_xor(m, o));
  __shared__ float red[4];
  if (lane == 0) red[wave] = m;
  __syncthreads();
  m = fmaxf(fmaxf(red[0], red[1]), fmaxf(red[2], red[3]));
  float s = 0.f;
  for (int j = t; j < 16384; j += 256) s += expf(p[j] - m);
#pragma unroll
  for (int o = 32; o; o >>= 1) s += __shfl_xor(s, o);
  __syncthreads();
  if (lane == 0) red[wave] = s;
  __syncthreads();
  s = red[0] + red[1] + red[2] + red[3];
  if (t == 0 && (1.f / s) > 0.9f) exited[tok] = 1;
}

// ---------------------------------------------------------------------------
// Host launch
// ---------------------------------------------------------------------------
extern "C" void kernel_launch(void* const* d_in, const int* in_sizes, int n_in,
                              void* d_out, int out_size, void* d_ws, size_t ws_size,
                              hipStream_t stream) {
  (void)out_size;
  const float* wte   = (const float*)d_in[0];
  const float* wpe   = (const float*)d_in[1];
  const float* ln1_g = (const float*)d_in[2];
  const float* ln1_b = (const float*)d_in[3];
  const float* wqkv  = (const float*)d_in[4];
  const float* wo    = (const float*)d_in[5];
  const float* ln2_g = (const float*)d_in[6];
  const float* ln2_b = (const float*)d_in[7];
  const float* w1    = (const float*)d_in[8];
  const float* b1    = (const float*)d_in[9];
  const float* w2    = (const float*)d_in[10];
  const float* b2    = (const float*)d_in[11];
  const float* eln_g = (const float*)d_in[12];
  const float* eln_b = (const float*)d_in[13];
  const float* ehead = (const float*)d_in[14];
  const int* idx = (const int*)d_in[15];
  float* out = (float*)d_out;  // f32 output (proven round 5)

  float sentinel = 0.f;
  if (!(n_in == 16 && in_sizes[0] == 4194304 && in_sizes[14] == 16777216 &&
        in_sizes[15] == 1024))
    sentinel += 1000.f;
  if (ws_size < (size_t)20000000) sentinel += 2000.f;

  char* w = (char*)d_ws;
  auto alloc = [&](size_t bytes) {
    char* p = w; w += (bytes + 255) & ~(size_t)255; return p;
  };
  int* i64f        = (int*)alloc(256);
  Scalars* sc      = (Scalars*)alloc(sizeof(Scalars));
  int* exited      = (int*)alloc(1024 * 4);
  float* norms     = (float*)alloc(1024 * 4);
  float* z_prev    = (float*)alloc(1024 * 256 * 4);
  float* z_s       = (float*)alloc(1024 * 256 * 4);
  float* attnout   = (float*)alloc(1024 * 256 * 4);
  float* dz        = (float*)alloc(1024 * 256 * 4);
  unsigned short* xln  = (unsigned short*)alloc(1024 * 256 * 2);
  unsigned short* hln  = (unsigned short*)alloc(1024 * 256 * 2);
  unsigned short* zn   = (unsigned short*)alloc(1024 * 256 * 2);
  unsigned short* qkvb = (unsigned short*)alloc((size_t)1024 * 768 * 2);
  unsigned short* obuf = (unsigned short*)alloc(1024 * 256 * 2);
  unsigned short* hmid = (unsigned short*)alloc((size_t)1024 * 1024 * 2);
  unsigned short* Sbuf = (unsigned short*)alloc((size_t)4 * 1024 * 1024 * 2);  // 8 MB (scores / bheadT)
  unsigned short* qkvT = (unsigned short*)alloc((size_t)768 * 256 * 2);
  unsigned short* woT  = (unsigned short*)alloc((size_t)256 * 256 * 2);
  unsigned short* w1T  = (unsigned short*)alloc((size_t)1024 * 256 * 2);
  unsigned short* w2T  = (unsigned short*)alloc((size_t)256 * 1024 * 2);
  unsigned short* VT   = (unsigned short*)alloc((size_t)4 * 64 * 1024 * 2);
  const int* guard = &sc->active;

  detect_idx_kernel<<<1, 256, 0, stream>>>(idx, i64f);
  embed_kernel<<<1024, 256, 0, stream>>>(wte, wpe, idx, z_prev, exited, i64f);

  for (int i = 0; i < 4; ++i) {
    // One-time per layer: weights -> bf16 [N,K] (conflict-free TRANSB staging)
    tr_weights_kernel<<<192, 256, 0, stream>>>(
        wqkv + (size_t)i * 196608, wo + (size_t)i * 65536,
        w1 + (size_t)i * 262144, w2 + (size_t)i * 262144,
        qkvT, woT, w1T, w2T);
    initblk_kernel<<<256, 256, 0, stream>>>(z_s, z_prev, sc);
    for (int s = 0; s < 4; ++s) {
      ln_kernel<<<256, 256, 0, stream>>>(z_s, ln1_g, ln1_b, i * 256, xln, guard);
      {  // qkv = ln1(z) @ wqkv[i] -> bf16 [1024,768] + VT (V transposed)
        GemmArgs a{}; a.A = xln; a.lda = 256;
        a.B = qkvT; a.ldb = 256;
        a.C = qkvb; a.ldc = 768; a.K = 256; a.guard = guard; a.C2 = VT;
        gemm_mfma<EPI_QKV_BF16><<<dim3(16, 12, 1), 256, 0, stream>>>(a);
      }
      {  // S_h = Q_h @ K_h^T * 0.125 causal -> bf16, batched over heads
        GemmArgs a{}; a.A = qkvb; a.lda = 768; a.aStrideZ = 64;
        a.B = qkvb; a.bOff = 256; a.ldb = 768; a.bStrideZ = 64;
        a.C = Sbuf; a.ldc = 1024; a.cStrideZ = 1048576; a.K = 64; a.guard = guard;
        gemm_mfma<EPI_SCORES_BF16><<<dim3(16, 16, 4), 256, 0, stream>>>(a);
      }
      softmax_kernel<<<dim3(1024, 4), 256, 0, stream>>>(Sbuf, guard);
      {  // O_h = P_h @ V_h -> obuf bf16 [1024,256]; causal K clamp
        GemmArgs a{}; a.A = Sbuf; a.lda = 1024; a.aStrideZ = 1048576;
        a.B = VT; a.ldb = 1024; a.bStrideZ = 65536;
        a.C = obuf; a.ldc = 256; a.cStrideZ = 64; a.K = 1024; a.causalK = 1;
        a.guard = guard;
        gemm_mfma<EPI_BF16><<<dim3(16, 1, 4), 256, 0, stream>>>(a);
      }
      {  // attnout = O @ wo[i] -> f32
        GemmArgs a{}; a.A = obuf; a.lda = 256;
        a.B = woT; a.ldb = 256;
        a.C = attnout; a.ldc = 256; a.K = 256; a.guard = guard;
        gemm_mfma<EPI_F32><<<dim3(16, 4, 1), 256, 0, stream>>>(a);
      }
      ln_kernel<<<256, 256, 0, stream>>>(z_s, ln2_g, ln2_b, i * 256, hln, guard);
      {  // hmid = gelu(ln2(z) @ w1[i] + b1[i]) -> bf16
        GemmArgs a{}; a.A = hln; a.lda = 256;
        a.B = w1T; a.ldb = 256;
        a.C = hmid; a.ldc = 1024; a.K = 256;
        a.bias = b1; a.biasOff = i * 1024; a.guard = guard;
        gemm_mfma<EPI_GELU_BF16><<<dim3(16, 16, 1), 256, 0, stream>>>(a);
      }
      {  // dz = hmid @ w2[i] + b2[i] + attnout -> f32
        GemmArgs a{}; a.A = hmid; a.lda = 1024;
        a.B = w2T; a.ldb = 1024;
        a.C = dz; a.ldc = 256; a.K = 1024;
        a.bias = b2; a.biasOff = i * 256; a.addsrc = attnout; a.guard = guard;
        gemm_mfma<EPI_ADD_F32><<<dim3(16, 4, 1), 256, 0, stream>>>(a);
      }
      norm_kernel<<<256, 256, 0, stream>>>(dz, norms, guard);
      scalar_kernel<<<1, 1024, 0, stream>>>(norms, sc);
      update_kernel<<<256, 256, 0, stream>>>(z_s, dz, sc);
    }
    combine_kernel<<<256, 256, 0, stream>>>(z_prev, z_s, exited);
    // Layer 0 logits are provably dead (exited all-false until after layer-1
    // conf, so layer 1 overwrites every row). Skip eln+GEMM for i==0.
    if (i >= 1) {
      ln_kernel<<<256, 256, 0, stream>>>(z_prev, eln_g, eln_b, i * 256, zn, nullptr);
      // ehead[i] -> bf16 [16384,256] in Sbuf (free: scores rewrite it next layer)
      tr_mat_kernel<<<dim3(256, 4), 256, 0, stream>>>(
          ehead + (size_t)i * 4194304, Sbuf);
      {  // blk_logits = ln(z) @ ehead[i] -> d_out (f32) where !exited
        GemmArgs a{}; a.A = zn; a.lda = 256;
        a.B = Sbuf; a.ldb = 256;
        a.C = out; a.ldc = 16384; a.K = 256; a.exited = exited; a.xcdswz = 1;
        gemm_mfma<EPI_COND_F32><<<dim3(16, 256, 1), 256, 0, stream>>>(a);
      }
      if (i < 3) conf_kernel<<<1024, 256, 0, stream>>>(out, exited);  // i=3 conf is dead
    }
  }

  sentinel_kernel<<<1, 1, 0, stream>>>(out, sentinel);
}

// Round 3
// 1577.483 us; speedup vs baseline: 1.3847x; 1.0406x over previous
//
#include <hip/hip_runtime.h>
#include <stdint.h>

typedef __bf16 bf16x8 __attribute__((ext_vector_type(8)));
typedef float f32x4 __attribute__((ext_vector_type(4)));
typedef unsigned short ushort8 __attribute__((ext_vector_type(8)));

#define DEV static __device__ __forceinline__

DEV float bf2f(unsigned short h) {
  union { unsigned u; float f; } v; v.u = ((unsigned)h) << 16; return v.f;
}
DEV unsigned short f2bf(float f) {
  union { float f; unsigned u; } v; v.f = f;
  unsigned r = v.u + 0x7fffu + ((v.u >> 16) & 1u);  // RNE
  return (unsigned short)(r >> 16);
}
DEV float gelu_f(float x) {  // jax.nn.gelu approximate=True (tanh)
  const float c = 0.7978845608028654f;
  return 0.5f * x * (1.f + tanhf(c * (x + 0.044715f * x * x * x)));
}

struct Scalars { int active; int step_active; int steps; float t; float dt; };

// idx width probe (int64 -> (id,0,id,0,...) viewed as int32). Proven harmless.
__global__ void detect_idx_kernel(const int* idx, int* i64f) {
  __shared__ int anyOdd, anyEven;
  if (threadIdx.x == 0) { anyOdd = 0; anyEven = 0; }
  __syncthreads();
  for (int j = threadIdx.x; j < 1024; j += 256) {
    int v = idx[j];
    if (j & 1) { if (v != 0) anyOdd = 1; }
    else       { if (v != 0) anyEven = 1; }
  }
  __syncthreads();
  if (threadIdx.x == 0) *i64f = (anyOdd == 0 && anyEven == 1) ? 1 : 0;
}

__global__ void sentinel_kernel(float* out, float val) {
  if (val != 0.f) out[0] = val;
}

// ---------------------------------------------------------------------------
// Transpose-convert: src f32 [R][C] row-major -> dst bf16 [C][R] row-major.
// ---------------------------------------------------------------------------
DEV void tr_tile(const float* src, unsigned short* dst, int R, int C,
                 int tx, int ty, float (*lds)[65]) {
  const int tid = threadIdx.x;
#pragma unroll
  for (int jj = 0; jj < 4; ++jj) {
    int r = jj * 16 + (tid >> 4);
    int c = (tid & 15) * 4;
    float4 v = *(const float4*)&src[(size_t)(ty * 64 + r) * C + tx * 64 + c];
    lds[r][c] = v.x; lds[r][c + 1] = v.y; lds[r][c + 2] = v.z; lds[r][c + 3] = v.w;
  }
  __syncthreads();
  const int lr = tid >> 2, seg = (tid & 3) * 16;
  ushort8 o0, o1;
#pragma unroll
  for (int e = 0; e < 8; ++e) o0[e] = f2bf(lds[seg + e][lr]);
#pragma unroll
  for (int e = 0; e < 8; ++e) o1[e] = f2bf(lds[seg + 8 + e][lr]);
  unsigned short* dp = dst + (size_t)(tx * 64 + lr) * R + ty * 64 + seg;
  *(ushort8*)dp = o0;
  *(ushort8*)(dp + 8) = o1;
}

// All four weight matrices of one layer in one launch (192 tiles).
// Also resets the ODE scalar state for the upcoming block (block 0, thread 0)
// -- placed here (not in combine_init) to avoid a same-kernel write/read race.
__global__ __launch_bounds__(256) void tr_weights_kernel(
    const float* wqkv, const float* wo, const float* w1, const float* w2,
    unsigned short* qkvT, unsigned short* woT, unsigned short* w1T,
    unsigned short* w2T, Scalars* sc) {
  if (blockIdx.x == 0 && threadIdx.x == 0) {
    sc->active = 1; sc->step_active = 0; sc->t = 0.f; sc->steps = 0; sc->dt = 0.f;
  }
  __shared__ float lds[64][65];
  int t = blockIdx.x;
  if (t < 48)       { tr_tile(wqkv, qkvT, 256, 768, t % 12, t / 12, lds); }
  else if (t < 64)  { t -= 48;  tr_tile(wo, woT, 256, 256, t % 4, t / 4, lds); }
  else if (t < 128) { t -= 64;  tr_tile(w1, w1T, 256, 1024, t % 16, t / 16, lds); }
  else              { t -= 128; tr_tile(w2, w2T, 1024, 256, t % 4, t / 4, lds); }
}

// ehead[i] f32 [256][16384] -> bheadT bf16 [16384][256] (into Sbuf).
__global__ __launch_bounds__(256) void tr_mat_kernel(const float* src,
                                                     unsigned short* dst) {
  __shared__ float lds[64][65];
  tr_tile(src, dst, 256, 16384, blockIdx.x, blockIdx.y, lds);
}

// ---------------------------------------------------------------------------
// MFMA bf16 GEMM: C[1024 x N] = A[1024 x K] * B^T. 64x64 tiles, 4 waves x
// (2x2 16x16x32 frags). A bf16 [M,K]; B bf16 [N,K] (all pre-transposed).
//   A-frag A[m=lane&15][k=quad*8+j]; B-frag B[k=quad*8+j][n=lane&15]
//   C/D: col=lane&15, row=quad*4+reg
// ---------------------------------------------------------------------------
enum { EPI_BF16 = 0, EPI_SCORES_BF16, EPI_GELU_BF16, EPI_F32, EPI_ADD_F32,
       EPI_COND_F32, EPI_QKV_BF16 };

struct GemmArgs {
  const unsigned short* A; int lda; long long aStrideZ;  // bf16 [M,K]
  const unsigned short* B; long long bOff; int ldb; long long bStrideZ;  // bf16 [N,K]
  void* C; int ldc; long long cStrideZ;
  int K;
  const float* bias; long long biasOff;  // f32
  const float* addsrc;
  const int* exited;
  const int* guard;
  unsigned short* C2;  // EPI_QKV: VT[4][64][1024] transposed V copy
  float* normsq;       // EPI_ADD_F32: per-row sum-of-squares accumulator
  int causalK;         // PV: kLimit = bm + 64
  int xcdswz;          // XCD-contiguous block remap (grid blocks % 8 == 0)
};

template <int EPI>
__global__ __launch_bounds__(256) void gemm_mfma(GemmArgs g) {
  if (g.guard && *g.guard == 0) return;
  int bx = blockIdx.x, by = blockIdx.y;
  if (g.xcdswz) {
    int lin = bx + gridDim.x * by;
    int cpx = (gridDim.x * gridDim.y) >> 3;
    int s2 = (lin & 7) * cpx + (lin >> 3);  // bijective: 4096 % 8 == 0
    bx = s2 % gridDim.x; by = s2 / gridDim.x;
  }
  const int bm = bx * 64;
  const int bn = by * 64;
  const int z = blockIdx.z;

  if constexpr (EPI == EPI_SCORES_BF16) {
    if (bn > bm) return;  // fully-masked tile: never read (softmax/PV clamp)
  }

  __shared__ __align__(16) unsigned short As[64][40];  // [m][k], 80B row
  __shared__ __align__(16) unsigned short Bs[64][40];  // [n][k]

  const int tid = threadIdx.x;
  const int lane = tid & 63;
  const int wave = tid >> 6;
  const int quad = lane >> 4, l16 = lane & 15;
  const int wr = (wave >> 1) * 32, wc = (wave & 1) * 32;
  const int rowA = tid >> 2, segA = (tid & 3) * 8;  // 64 rows x 32 k

  f32x4 acc[2][2] = {};
  const unsigned short* Az = g.A + (size_t)z * g.aStrideZ;
  const unsigned short* Bz = g.B + g.bOff + (size_t)z * g.bStrideZ;
  const int kLimit = g.causalK ? (bm + 64) : g.K;

  for (int k0 = 0; k0 < kLimit; k0 += 32) {
    *(ushort8*)&As[rowA][segA] =
        *(const ushort8*)(Az + (size_t)(bm + rowA) * g.lda + k0 + segA);
    *(ushort8*)&Bs[rowA][segA] =
        *(const ushort8*)(Bz + (size_t)(bn + rowA) * g.ldb + k0 + segA);
    __syncthreads();

    bf16x8 a0 = *(const bf16x8*)&As[wr + l16][quad * 8];
    bf16x8 a1 = *(const bf16x8*)&As[wr + 16 + l16][quad * 8];
    bf16x8 b0 = *(const bf16x8*)&Bs[wc + l16][quad * 8];
    bf16x8 b1 = *(const bf16x8*)&Bs[wc + 16 + l16][quad * 8];
    acc[0][0] = __builtin_amdgcn_mfma_f32_16x16x32_bf16(a0, b0, acc[0][0], 0, 0, 0);
    acc[0][1] = __builtin_amdgcn_mfma_f32_16x16x32_bf16(a0, b1, acc[0][1], 0, 0, 0);
    acc[1][0] = __builtin_amdgcn_mfma_f32_16x16x32_bf16(a1, b0, acc[1][0], 0, 0, 0);
    acc[1][1] = __builtin_amdgcn_mfma_f32_16x16x32_bf16(a1, b1, acc[1][1], 0, 0, 0);
    __syncthreads();
  }

  if constexpr (EPI == EPI_ADD_F32) {
    // dz write + fused per-row sum-of-squares (replaces norm_kernel)
#pragma unroll
    for (int i2 = 0; i2 < 2; ++i2) {
#pragma unroll
      for (int r = 0; r < 4; ++r) {
        int row = bm + wr + i2 * 16 + quad * 4 + r;
        float sq = 0.f;
#pragma unroll
        for (int j = 0; j < 2; ++j) {
          int col = bn + wc + j * 16 + l16;
          float val = acc[i2][j][r] + g.bias[g.biasOff + col] +
                      g.addsrc[(size_t)row * g.ldc + col];
          ((float*)g.C)[(size_t)row * g.ldc + col] = val;
          sq += val * val;
        }
        sq += __shfl_xor(sq, 1); sq += __shfl_xor(sq, 2);
        sq += __shfl_xor(sq, 4); sq += __shfl_xor(sq, 8);
        if (l16 == 0) atomicAdd(g.normsq + row, sq);
      }
    }
    return;
  }

#pragma unroll
  for (int i = 0; i < 2; ++i) {
#pragma unroll
    for (int j = 0; j < 2; ++j) {
#pragma unroll
      for (int r = 0; r < 4; ++r) {
        int row = bm + wr + i * 16 + quad * 4 + r;
        int col = bn + wc + j * 16 + l16;
        float val = acc[i][j][r];
        if constexpr (EPI == EPI_BF16) {
          ((unsigned short*)g.C)[(size_t)z * g.cStrideZ + (size_t)row * g.ldc + col] =
              f2bf(val);
        } else if constexpr (EPI == EPI_QKV_BF16) {
          unsigned short bv = f2bf(val);
          ((unsigned short*)g.C)[(size_t)row * g.ldc + col] = bv;
          if (col >= 512) {  // also write V transposed: VT[h][hd][tok]
            int cc = col - 512;
            g.C2[((cc >> 6) << 16) + ((cc & 63) << 10) + row] = bv;
          }
        } else if constexpr (EPI == EPI_SCORES_BF16) {
          float o = (col <= row) ? val * 0.125f : -1e9f;  // 1/sqrt(64) + causal
          ((unsigned short*)g.C)[(size_t)z * g.cStrideZ + (size_t)row * g.ldc + col] =
              f2bf(o);
        } else if constexpr (EPI == EPI_GELU_BF16) {
          ((unsigned short*)g.C)[(size_t)row * g.ldc + col] =
              f2bf(gelu_f(val + g.bias[g.biasOff + col]));
        } else if constexpr (EPI == EPI_F32) {
          ((float*)g.C)[(size_t)z * g.cStrideZ + (size_t)row * g.ldc + col] = val;
        } else if constexpr (EPI == EPI_COND_F32) {
          if (!g.exited[row])
            ((float*)g.C)[(size_t)row * g.ldc + col] = val;
        }
      }
    }
  }
}

// ---------------------------------------------------------------------------
// Small kernels (f32 state, bf16 MFMA feeds)
// ---------------------------------------------------------------------------
// embed also initializes z_s (solver state for layer 0) and the ODE scalars.
__global__ void embed_kernel(const float* wte, const float* wpe, const int* idx,
                             float* z_prev, float* z_s, int* exited,
                             const int* i64f, Scalars* sc) {
  int tok = blockIdx.x, d = threadIdx.x;
  int id = (*i64f) ? idx[2 * tok] : idx[tok];
  float v = wte[(size_t)id * 256 + d] + wpe[(size_t)tok * 256 + d];
  z_prev[tok * 256 + d] = v;
  z_s[tok * 256 + d] = v;
  if (d == 0) exited[tok] = 0;
  if (tok == 0 && d == 0) {
    sc->active = 1; sc->step_active = 0; sc->t = 0.f; sc->steps = 0; sc->dt = 0.f;
  }
}

// Fused step head: apply pending Euler update (from previous step's scalar),
// then layernorm z_s once, emitting BOTH ln1 and ln2 outputs (shared mean/var).
// Also zeroes the normsq accumulator for this step's w2 epilogue.
__global__ void upln_kernel(float* z_s, const float* dz,
                            const float* g1, const float* b1v,
                            const float* g2, const float* b2v, int goff,
                            unsigned short* xln, unsigned short* hln,
                            float* normsq, const Scalars* sc) {
  const int sa = sc->step_active, act = sc->active;
  if (!sa && !act) return;
  int wave = threadIdx.x >> 6, lane = threadIdx.x & 63;
  int tok = blockIdx.x * 4 + wave;
  float* p = z_s + (size_t)tok * 256;
  float v[4];
#pragma unroll
  for (int j = 0; j < 4; ++j) v[j] = p[lane + 64 * j];
  if (sa) {
    float dt = sc->dt;
    const float* d = dz + (size_t)tok * 256;
#pragma unroll
    for (int j = 0; j < 4; ++j) {
      v[j] += dt * d[lane + 64 * j];
      p[lane + 64 * j] = v[j];
    }
  }
  if (!act) return;
  if (blockIdx.x == 0) {
#pragma unroll
    for (int j = 0; j < 4; ++j) normsq[threadIdx.x * 4 + j] = 0.f;
  }
  float s = 0.f, s2 = 0.f;
#pragma unroll
  for (int j = 0; j < 4; ++j) { s += v[j]; s2 += v[j] * v[j]; }
#pragma unroll
  for (int o = 1; o < 64; o <<= 1) { s += __shfl_xor(s, o); s2 += __shfl_xor(s2, o); }
  float mean = s * (1.f / 256.f);
  float var = s2 * (1.f / 256.f) - mean * mean;
  float rstd = rsqrtf(var + 1e-5f);
#pragma unroll
  for (int j = 0; j < 4; ++j) {
    int d = lane + 64 * j;
    float xv = (v[j] - mean) * rstd;
    xln[(size_t)tok * 256 + d] = f2bf(xv * g1[goff + d] + b1v[goff + d]);
    hln[(size_t)tok * 256 + d] = f2bf(xv * g2[goff + d] + b2v[goff + d]);
  }
}

// layernorm (exit-head): f32 in -> bf16 out, one wave per token
__global__ void ln_kernel(const float* x, const float* gg, const float* bb, int goff,
                          unsigned short* out) {
  int wave = threadIdx.x >> 6, lane = threadIdx.x & 63;
  int tok = blockIdx.x * 4 + wave;
  const float* p = x + (size_t)tok * 256;
  float v[4];
  float s = 0.f, s2 = 0.f;
#pragma unroll
  for (int j = 0; j < 4; ++j) { v[j] = p[lane + 64 * j]; s += v[j]; s2 += v[j] * v[j]; }
#pragma unroll
  for (int o = 1; o < 64; o <<= 1) { s += __shfl_xor(s, o); s2 += __shfl_xor(s2, o); }
  float mean = s * (1.f / 256.f);
  float var = s2 * (1.f / 256.f) - mean * mean;
  float rstd = rsqrtf(var + 1e-5f);
#pragma unroll
  for (int j = 0; j < 4; ++j) {
    int d = lane + 64 * j;
    out[(size_t)tok * 256 + d] = f2bf((v[j] - mean) * rstd * gg[goff + d] + bb[goff + d]);
  }
}

// softmax in-place over bf16 rows of S[head][1024][1024], clamped to the
// causal prefix. Cols beyond rowEnd never read downstream (PV clamps K).
__global__ __launch_bounds__(256) void softmax_kernel(unsigned short* S,
                                                      const int* guard) {
  if (*guard == 0) return;
  int row = blockIdx.x, h = blockIdx.y;
  unsigned short* p = S + ((size_t)h << 20) + ((size_t)row << 10);
  int t = threadIdx.x, lane = t & 63, wave = t >> 6;
  int rowEnd = (row & ~63) + 64;
  bool act = (t * 4) < rowEnd;
  float v0 = -1e30f, v1 = -1e30f, v2 = -1e30f, v3 = -1e30f;
  if (act) {
    ushort4 u = ((ushort4*)p)[t];
    v0 = bf2f(u.x); v1 = bf2f(u.y); v2 = bf2f(u.z); v3 = bf2f(u.w);
  }
  float m = fmaxf(fmaxf(v0, v1), fmaxf(v2, v3));
#pragma unroll
  for (int o = 32; o; o >>= 1) m = fmaxf(m, __shfl_xor(m, o));
  __shared__ float red[4];
  if (lane == 0) red[wave] = m;
  __syncthreads();
  m = fmaxf(fmaxf(red[0], red[1]), fmaxf(red[2], red[3]));
  float e0 = expf(v0 - m), e1 = expf(v1 - m), e2 = expf(v2 - m), e3 = expf(v3 - m);
  float s = e0 + e1 + e2 + e3;
#pragma unroll
  for (int o = 32; o; o >>= 1) s += __shfl_xor(s, o);
  __syncthreads();
  if (lane == 0) red[wave] = s;
  __syncthreads();
  s = red[0] + red[1] + red[2] + red[3];
  float inv = 1.f / s;
  if (act) {
    ushort4 w; w.x = f2bf(e0 * inv); w.y = f2bf(e1 * inv);
    w.z = f2bf(e2 * inv); w.w = f2bf(e3 * inv);
    ((ushort4*)p)[t] = w;
  }
}

__global__ __launch_bounds__(1024) void scalar_kernel(const float* normsq, Scalars* sc) {
  __shared__ float red[1024];
  if (sc->active == 0) { if (threadIdx.x == 0) sc->step_active = 0; return; }
  int t = threadIdx.x;
  red[t] = sqrtf(normsq[t]);
  __syncthreads();
  for (int o = 512; o; o >>= 1) { if (t < o) red[t] += red[t + o]; __syncthreads(); }
  if (t == 0) {
    float mc = red[0] * (1.f / 1024.f);
    float scale = fminf(fmaxf(1.f / (1.f + mc), 0.5f), 2.f);
    float dt = fminf(0.5f * scale, 1.f - sc->t);  // dt_base = 1/MIN_STEPS
    sc->dt = dt;
    sc->step_active = 1;
    float tn = sc->t + dt;
    int steps = sc->steps + 1;
    sc->t = tn;
    sc->steps = steps;
    int conv = (dt * mc < 0.1f) && (steps >= 2);  // ||z_new-z|| = dt*||dz||
    sc->active = ((tn < 1.f - 1e-6f) && !conv) ? 1 : 0;
  }
}

// combine (z_prev += solver state, masked by exited) fused with next-layer
// solver-state init. Applies the final pending Euler update first.
// NOTE: does NOT reset sc (tr_weights of the next layer does) -- avoids a
// write/read race on sc->step_active across blocks of this kernel.
__global__ void combine_init_kernel(float* z_prev, float* z_s, const float* dz,
                                    const int* exited, const Scalars* sc) {
  int i = blockIdx.x * 256 + threadIdx.x;
  int tok = i >> 6;
  float4 b = ((float4*)z_s)[i];
  if (sc->step_active) {
    float dt = sc->dt;
    float4 d = ((const float4*)dz)[i];
    b.x += dt * d.x; b.y += dt * d.y; b.z += dt * d.z; b.w += dt * d.w;
  }
  float4 a = ((float4*)z_prev)[i];
  if (!exited[tok]) {
    a.x += b.x; a.y += b.y; a.z += b.z; a.w += b.w;
    ((float4*)z_prev)[i] = a;
  }
  ((float4*)z_s)[i] = a;
}

__global__ __launch_bounds__(256) void conf_kernel(const float* logits, int* exited) {
  int tok = blockIdx.x;
  if (exited[tok]) return;
  const float* p = logits + ((size_t)tok << 14);
  int t = threadIdx.x, lane = t & 63, wave = t >> 6;
  // pass 1: float4-vectorized max (fmax is order-invariant -> bitwise same m)
  float m = -1e30f;
  const float4* p4 = (const float4*)p;
  for (int j = t; j < 4096; j += 256) {
    float4 u = p4[j];
    m = fmaxf(fmaxf(fmaxf(m, u.x), u.y), fmaxf(u.z, u.w));
  }
#pragma unroll
  for (int o = 32; o; o >>= 1) m = fmaxf(m, __shfl_xor(m, o));
  __shared__ float red[4];
  if (lane == 0) red[wave] = m;
  __syncthreads();
  m = fmaxf(fmaxf(red[0], red[1]), fmaxf(red[2], red[3]));
  // pass 2: exact original element order (L2-hot after pass 1)
  float s = 0.f;
  for (int j = t; j < 16384; j += 256) s += expf(p[j] - m);
#pragma unroll
  for (int o = 32; o; o >>= 1) s += __shfl_xor(s, o);
  __syncthreads();
  if (lane == 0) red[wave] = s;
  __syncthreads();
  s = red[0] + red[1] + red[2] + red[3];
  if (t == 0 && (1.f / s) > 0.9f) exited[tok] = 1;
}

// ---------------------------------------------------------------------------
// Host launch
// ---------------------------------------------------------------------------
extern "C" void kernel_launch(void* const* d_in, const int* in_sizes, int n_in,
                              void* d_out, int out_size, void* d_ws, size_t ws_size,
                              hipStream_t stream) {
  (void)out_size;
  const float* wte   = (const float*)d_in[0];
  const float* wpe   = (const float*)d_in[1];
  const float* ln1_g = (const float*)d_in[2];
  const float* ln1_b = (const float*)d_in[3];
  const float* wqkv  = (const float*)d_in[4];
  const float* wo    = (const float*)d_in[5];
  const float* ln2_g = (const float*)d_in[6];
  const float* ln2_b = (const float*)d_in[7];
  const float* w1    = (const float*)d_in[8];
  const float* b1    = (const float*)d_in[9];
  const float* w2    = (const float*)d_in[10];
  const float* b2    = (const float*)d_in[11];
  const float* eln_g = (const float*)d_in[12];
  const float* eln_b = (const float*)d_in[13];
  const float* ehead = (const float*)d_in[14];
  const int* idx = (const int*)d_in[15];
  float* out = (float*)d_out;  // f32 output

  float sentinel = 0.f;
  if (!(n_in == 16 && in_sizes[0] == 4194304 && in_sizes[14] == 16777216 &&
        in_sizes[15] == 1024))
    sentinel += 1000.f;
  if (ws_size < (size_t)20000000) sentinel += 2000.f;

  char* w = (char*)d_ws;
  auto alloc = [&](size_t bytes) {
    char* p = w; w += (bytes + 255) & ~(size_t)255; return p;
  };
  int* i64f        = (int*)alloc(256);
  Scalars* sc      = (Scalars*)alloc(sizeof(Scalars));
  int* exited      = (int*)alloc(1024 * 4);
  float* normsq    = (float*)alloc(1024 * 4);
  float* z_prev    = (float*)alloc(1024 * 256 * 4);
  float* z_s       = (float*)alloc(1024 * 256 * 4);
  float* attnout   = (float*)alloc(1024 * 256 * 4);
  float* dz        = (float*)alloc(1024 * 256 * 4);
  unsigned short* xln  = (unsigned short*)alloc(1024 * 256 * 2);
  unsigned short* hln  = (unsigned short*)alloc(1024 * 256 * 2);
  unsigned short* zn   = (unsigned short*)alloc(1024 * 256 * 2);
  unsigned short* qkvb = (unsigned short*)alloc((size_t)1024 * 768 * 2);
  unsigned short* obuf = (unsigned short*)alloc(1024 * 256 * 2);
  unsigned short* hmid = (unsigned short*)alloc((size_t)1024 * 1024 * 2);
  unsigned short* Sbuf = (unsigned short*)alloc((size_t)4 * 1024 * 1024 * 2);  // 8 MB (scores / bheadT)
  unsigned short* qkvT = (unsigned short*)alloc((size_t)768 * 256 * 2);
  unsigned short* woT  = (unsigned short*)alloc((size_t)256 * 256 * 2);
  unsigned short* w1T  = (unsigned short*)alloc((size_t)1024 * 256 * 2);
  unsigned short* w2T  = (unsigned short*)alloc((size_t)256 * 1024 * 2);
  unsigned short* VT   = (unsigned short*)alloc((size_t)4 * 64 * 1024 * 2);
  const int* guard = &sc->active;

  detect_idx_kernel<<<1, 256, 0, stream>>>(idx, i64f);
  embed_kernel<<<1024, 256, 0, stream>>>(wte, wpe, idx, z_prev, z_s, exited,
                                         i64f, sc);

  for (int i = 0; i < 4; ++i) {
    // One-time per layer: weights -> bf16 [N,K]; also resets ODE scalars.
    tr_weights_kernel<<<192, 256, 0, stream>>>(
        wqkv + (size_t)i * 196608, wo + (size_t)i * 65536,
        w1 + (size_t)i * 262144, w2 + (size_t)i * 262144,
        qkvT, woT, w1T, w2T, sc);
    for (int s = 0; s < 4; ++s) {
      // fused: pending Euler update + ln1 + ln2 (+ normsq zero)
      upln_kernel<<<256, 256, 0, stream>>>(z_s, dz, ln1_g, ln1_b, ln2_g, ln2_b,
                                           i * 256, xln, hln, normsq, sc);
      {  // qkv = ln1(z) @ wqkv[i] -> bf16 [1024,768] + VT (V transposed)
        GemmArgs a{}; a.A = xln; a.lda = 256;
        a.B = qkvT; a.ldb = 256;
        a.C = qkvb; a.ldc = 768; a.K = 256; a.guard = guard; a.C2 = VT;
        gemm_mfma<EPI_QKV_BF16><<<dim3(16, 12, 1), 256, 0, stream>>>(a);
      }
      {  // S_h = Q_h @ K_h^T * 0.125 causal -> bf16, batched over heads
        GemmArgs a{}; a.A = qkvb; a.lda = 768; a.aStrideZ = 64;
        a.B = qkvb; a.bOff = 256; a.ldb = 768; a.bStrideZ = 64;
        a.C = Sbuf; a.ldc = 1024; a.cStrideZ = 1048576; a.K = 64; a.guard = guard;
        gemm_mfma<EPI_SCORES_BF16><<<dim3(16, 16, 4), 256, 0, stream>>>(a);
      }
      softmax_kernel<<<dim3(1024, 4), 256, 0, stream>>>(Sbuf, guard);
      {  // O_h = P_h @ V_h -> obuf bf16 [1024,256]; causal K clamp
        GemmArgs a{}; a.A = Sbuf; a.lda = 1024; a.aStrideZ = 1048576;
        a.B = VT; a.ldb = 1024; a.bStrideZ = 65536;
        a.C = obuf; a.ldc = 256; a.cStrideZ = 64; a.K = 1024; a.causalK = 1;
        a.guard = guard;
        gemm_mfma<EPI_BF16><<<dim3(16, 1, 4), 256, 0, stream>>>(a);
      }
      {  // attnout = O @ wo[i] -> f32
        GemmArgs a{}; a.A = obuf; a.lda = 256;
        a.B = woT; a.ldb = 256;
        a.C = attnout; a.ldc = 256; a.K = 256; a.guard = guard;
        gemm_mfma<EPI_F32><<<dim3(16, 4, 1), 256, 0, stream>>>(a);
      }
      {  // hmid = gelu(ln2(z) @ w1[i] + b1[i]) -> bf16
        GemmArgs a{}; a.A = hln; a.lda = 256;
        a.B = w1T; a.ldb = 256;
        a.C = hmid; a.ldc = 1024; a.K = 256;
        a.bias = b1; a.biasOff = i * 1024; a.guard = guard;
        gemm_mfma<EPI_GELU_BF16><<<dim3(16, 16, 1), 256, 0, stream>>>(a);
      }
      {  // dz = hmid @ w2[i] + b2[i] + attnout -> f32; fused row-norm accum
        GemmArgs a{}; a.A = hmid; a.lda = 1024;
        a.B = w2T; a.ldb = 1024;
        a.C = dz; a.ldc = 256; a.K = 1024;
        a.bias = b2; a.biasOff = i * 256; a.addsrc = attnout;
        a.normsq = normsq; a.guard = guard;
        gemm_mfma<EPI_ADD_F32><<<dim3(16, 4, 1), 256, 0, stream>>>(a);
      }
      scalar_kernel<<<1, 1024, 0, stream>>>(normsq, sc);
    }
    // combine + next-layer init (applies final pending update; no sc reset)
    combine_init_kernel<<<256, 256, 0, stream>>>(z_prev, z_s, dz, exited, sc);
    // Layer 0 logits are provably dead (exited all-false until after layer-1
    // conf, so layer 1 overwrites every row). Skip eln+GEMM for i==0.
    if (i >= 1) {
      ln_kernel<<<256, 256, 0, stream>>>(z_prev, eln_g, eln_b, i * 256, zn);
      // ehead[i] -> bf16 [16384,256] in Sbuf (scores rewrite it next layer)
      tr_mat_kernel<<<dim3(256, 4), 256, 0, stream>>>(
          ehead + (size_t)i * 4194304, Sbuf);
      {  // blk_logits = ln(z) @ ehead[i] -> d_out (f32) where !exited
        GemmArgs a{}; a.A = zn; a.lda = 256;
        a.B = Sbuf; a.ldb = 256;
        a.C = out; a.ldc = 16384; a.K = 256; a.exited = exited; a.xcdswz = 1;
        gemm_mfma<EPI_COND_F32><<<dim3(16, 256, 1), 256, 0, stream>>>(a);
      }
      if (i < 3) conf_kernel<<<1024, 256, 0, stream>>>(out, exited);  // i=3 conf dead
    }
  }

  sentinel_kernel<<<1, 1, 0, stream>>>(out, sentinel);
}